// Round 7
// baseline (140.364 us; speedup 1.0000x reference)
//
#include <hip/hip_runtime.h>
#include <stdint.h>

// VectorQuantizer on MI355X (gfx950), fp32 exact path, round 7.
// R6 diagnosis: 1 pt/lane => 4 B of s_load per FMA instr; 128 KB w stream
// misses the scalar K$ and SGPR-limited prefetch can't cover L2 latency at
// 4 waves/SIMD -> 47% busy. R4 proved 2 pts/lane at 64% busy. This round:
// thread = 2 pts x 16 codes (acc[32]); block = 8 waves = 128 pts; each wave
// kb-loops 4x over stride-128 code groups => all 512 codes in-block (LDS
// argmin merge + fused epilogue, zero global atomics on keys, no transpose).
// x read straight from x_in (float4 pairs) with explicit next-d8 prefetch.

#define DDIM 64
#define KCODES 512

// ws: wT 131072 B @ 0, wsq 2048 B @ 131072

__global__ void vq_prep(const float* __restrict__ w, float* __restrict__ wT,
                        float* __restrict__ wsq, float* __restrict__ loss_out) {
  int g = blockIdx.x * 256 + threadIdx.x;  // 128 blocks over D*K
  int d = g >> 9, k = g & 511;
  wT[k * DDIM + d] = w[g];                 // [K][D] for epilogue gather
  if (g < KCODES) {
    float s = 0.f;
    for (int dd = 0; dd < DDIM; ++dd) {
      float t = w[dd * KCODES + g];
      s = fmaf(t, t, s);
    }
    wsq[g] = s;
  }
  if (g == 0) *loss_out = 0.f;             // d_out is poisoned each launch
}

__global__ __launch_bounds__(512, 4)
void vq_main(const float* __restrict__ x_in, const float* __restrict__ w,
             const float* __restrict__ wT, const float* __restrict__ wsq,
             float* __restrict__ out_q, float* __restrict__ out_idx,
             float* __restrict__ loss_out) {
  __shared__ unsigned long long sm_key[8][128];  // per-wave partial keys
  __shared__ unsigned int sm_idx[128];
  __shared__ float sm_sx[128];
  __shared__ float sm_loss[128];

  const int t = threadIdx.x;
  const int pb = blockIdx.x;                              // 512 blocks, 128 pts
  const int wv = __builtin_amdgcn_readfirstlane(t >> 6);  // wave id 0..7 (SGPR)
  const int lane = t & 63;
  const int p0 = (pb << 7) | (lane << 1);                 // two adjacent points

  const float* xa = x_in + (size_t)p0 * DDIM;
  const float* xb = xa + DDIM;

  float best0 = 3.0e38f, best1 = 3.0e38f;
  int bi0 = 0, bi1 = 0;
  float sx0 = 0.f, sx1 = 0.f;

#pragma unroll 1
  for (int kb = 0; kb < 4; ++kb) {
    // wave's 16-code group this round; increases with kb -> first-min order ok
    const int k0 = (wv << 4) + (kb << 7);
    const float* wp = w + k0;              // SGPR-rooted -> s_load promotion
    float acc0[16], acc1[16];
#pragma unroll
    for (int c = 0; c < 16; ++c) { acc0[c] = 0.f; acc1[c] = 0.f; }

    float4 c00 = *(const float4*)(xa + 0);
    float4 c01 = *(const float4*)(xa + 4);
    float4 c10 = *(const float4*)(xb + 0);
    float4 c11 = *(const float4*)(xb + 4);
#pragma unroll 1
    for (int d8 = 0; d8 < 8; ++d8) {
      // software prefetch of next d8 (tail re-reads d=56..63, harmless)
      const int dn = (d8 < 7) ? (d8 + 1) * 8 : 56;
      float4 n00 = *(const float4*)(xa + dn);
      float4 n01 = *(const float4*)(xa + dn + 4);
      float4 n10 = *(const float4*)(xb + dn);
      float4 n11 = *(const float4*)(xb + dn + 4);
      const float xv0[8] = {c00.x, c00.y, c00.z, c00.w,
                            c01.x, c01.y, c01.z, c01.w};
      const float xv1[8] = {c10.x, c10.y, c10.z, c10.w,
                            c11.x, c11.y, c11.z, c11.w};
      if (wv == 0 && kb == 0) {  // wave-uniform: ||x||^2 once per point
#pragma unroll
        for (int dd = 0; dd < 8; ++dd) {
          sx0 = fmaf(xv0[dd], xv0[dd], sx0);
          sx1 = fmaf(xv1[dd], xv1[dd], sx1);
        }
      }
#pragma unroll
      for (int dd = 0; dd < 8; ++dd) {
        const float* wd = wp + (((d8 << 3) + dd) << 9);  // w[d][k0..k0+15]
#pragma unroll
        for (int c = 0; c < 16; ++c) {
          float wvv = wd[c];               // wave-uniform -> SGPR operand
          acc0[c] = fmaf(wvv, xv0[dd], acc0[c]);
          acc1[c] = fmaf(wvv, xv1[dd], acc1[c]);
        }
      }
      c00 = n00; c01 = n01; c10 = n10; c11 = n11;
    }
#pragma unroll
    for (int c = 0; c < 16; ++c) {
      float wq = wsq[k0 + c];
      float d0 = fmaf(acc0[c], -2.0f, wq);
      float d1 = fmaf(acc1[c], -2.0f, wq);
      if (d0 < best0) { best0 = d0; bi0 = k0 + c; }  // strict <: first-min
      if (d1 < best1) { best1 = d1; bi1 = k0 + c; }
    }
  }

  // sortable-float pack, idx in low bits -> exact ties pick lowest index
  unsigned int u0 = __float_as_uint(best0);
  u0 = (u0 & 0x80000000u) ? ~u0 : (u0 | 0x80000000u);
  unsigned int u1 = __float_as_uint(best1);
  u1 = (u1 & 0x80000000u) ? ~u1 : (u1 | 0x80000000u);
  sm_key[wv][lane << 1] =
      ((unsigned long long)u0 << 32) | (unsigned long long)(unsigned int)bi0;
  sm_key[wv][(lane << 1) | 1] =
      ((unsigned long long)u1 << 32) | (unsigned long long)(unsigned int)bi1;
  if (wv == 0) { sm_sx[lane << 1] = sx0; sm_sx[(lane << 1) | 1] = sx1; }
  __syncthreads();

  // merge the 8 per-wave candidates for each of the 128 points
  if (t < 128) {
    unsigned long long k = sm_key[0][t];
#pragma unroll
    for (int wi = 1; wi < 8; ++wi) {
      unsigned long long k2 = sm_key[wi][t];
      k = k2 < k ? k2 : k;
    }
    unsigned int idx = (unsigned int)k;
    sm_idx[t] = idx;
    out_idx[(size_t)pb * 128 + t] = (float)idx;
    unsigned int u = (unsigned int)(k >> 32);
    u = (u & 0x80000000u) ? (u & 0x7FFFFFFFu) : ~u;
    // ||x-q||^2 = ||x||^2 + (||q||^2 - 2 x.q), pre-scaled by 1.25/(N*D)
    sm_loss[t] = (__uint_as_float(u) + sm_sx[t]) * (1.25f / 4194304.0f);
  }
  __syncthreads();

  // epilogue: gather code rows, coalesced 128x64 tile write (2048 float4)
  float4* dst = (float4*)(out_q + (size_t)pb * 8192);
#pragma unroll
  for (int i = 0; i < 4; ++i) {
    int e = i * 512 + t;
    int p2 = e >> 4, d4 = e & 15;
    unsigned int idx = sm_idx[p2];                       // LDS broadcast
    dst[e] = ((const float4*)(wT + (size_t)idx * DDIM))[d4];  // L2-hot
  }

  // block loss partial -> single atomic (512 adds total)
  if (t < 64) {
    float s = sm_loss[t] + sm_loss[t + 64];
#pragma unroll
    for (int off = 32; off > 0; off >>= 1) s += __shfl_down(s, off);
    if (t == 0) atomicAdd(loss_out, s);
  }
}

extern "C" void kernel_launch(void* const* d_in, const int* in_sizes, int n_in,
                              void* d_out, int out_size, void* d_ws, size_t ws_size,
                              hipStream_t stream) {
  const float* x = (const float*)d_in[0];  // (64,32,32,64) fp32
  const float* w = (const float*)d_in[1];  // (64,512) fp32

  char* ws = (char*)d_ws;
  float* wT = (float*)(ws);
  float* wsq = (float*)(ws + 131072);

  float* out_q = (float*)d_out;            // 4194304 floats
  float* out_idx = out_q + 4194304;        // 65536 floats (indices)
  float* loss_out = out_q + 4259840;       // 1 float

  vq_prep<<<128, 256, 0, stream>>>(w, wT, wsq, loss_out);
  vq_main<<<512, 512, 0, stream>>>(x, w, wT, wsq, out_q, out_idx, loss_out);
}